// Round 1
// baseline (259.333 us; speedup 1.0000x reference)
//
#include <hip/hip_runtime.h>

// NCC loss: per-batch global sums + masked count, then scalar combine.
// SHAPE (16,1,64,128,128): B=16 volumes of VOL=1048576 f32 elements.
// Memory-bound: 256 MiB read total -> target ~45-60 us.

#define NB   16
#define VOL  (64 * 128 * 128)   // 1048576
#define BPB  256                // blocks per batch
#define TPB  256                // threads per block
#define EPT  16                 // elements per thread (4 x float4); BPB*TPB*EPT == VOL

__device__ __forceinline__ double wave_reduce(double v) {
    #pragma unroll
    for (int off = 32; off > 0; off >>= 1) v += __shfl_down(v, off, 64);
    return v;
}

__global__ __launch_bounds__(TPB) void ncc_partial(
    const float* __restrict__ I, const float* __restrict__ J,
    const int* __restrict__ CI, const int* __restrict__ CJ,
    double* __restrict__ part)
{
    const int b = blockIdx.y;
    const size_t base = (size_t)b * VOL + (size_t)blockIdx.x * (TPB * EPT);
    const int tid = threadIdx.x;

    const float4* I4 = reinterpret_cast<const float4*>(I + base);
    const float4* J4 = reinterpret_cast<const float4*>(J + base);
    const int4*   C4 = reinterpret_cast<const int4*>(CI + base);
    const int4*   D4 = reinterpret_cast<const int4*>(CJ + base);

    double sI = 0.0, sJ = 0.0, sI2 = 0.0, sJ2 = 0.0, sIJ = 0.0;
    int cnt = 0;

    #pragma unroll
    for (int k = 0; k < EPT / 4; ++k) {
        const int idx = tid + k * TPB;           // coalesced: 16B/lane
        float4 iv = I4[idx];
        float4 jv = J4[idx];
        int4   cv = C4[idx];
        int4   dv = D4[idx];

        float fi[4] = {iv.x, iv.y, iv.z, iv.w};
        float fj[4] = {jv.x, jv.y, jv.z, jv.w};
        int   ki[4] = {cv.x, cv.y, cv.z, cv.w};
        int   kj[4] = {dv.x, dv.y, dv.z, dv.w};

        #pragma unroll
        for (int e = 0; e < 4; ++e) {
            double di = (double)fi[e];
            double dj = (double)fj[e];
            sI += di;
            sJ += dj;
            sI2 = fma(di, di, sI2);
            sJ2 = fma(dj, dj, sJ2);
            sIJ = fma(di, dj, sIJ);
            // mask_I == 0 iff (I < 0.247 && CI > 0); compare in f64 to match np ref
            bool zI = (di < 0.247) && (ki[e] > 0);
            bool zJ = (dj < 0.247) && (kj[e] > 0);
            cnt += (!zI && !zJ) ? 1 : 0;
        }
    }

    double v[6] = {sI, sJ, sI2, sJ2, sIJ, (double)cnt};
    #pragma unroll
    for (int q = 0; q < 6; ++q) v[q] = wave_reduce(v[q]);

    __shared__ double sh[TPB / 64][6];
    const int wave = tid >> 6, lane = tid & 63;
    if (lane == 0) {
        #pragma unroll
        for (int q = 0; q < 6; ++q) sh[wave][q] = v[q];
    }
    __syncthreads();

    if (tid == 0) {
        double o[6] = {0, 0, 0, 0, 0, 0};
        for (int w = 0; w < TPB / 64; ++w)
            for (int q = 0; q < 6; ++q) o[q] += sh[w][q];
        double* p = part + ((size_t)b * BPB + blockIdx.x) * 6;
        #pragma unroll
        for (int q = 0; q < 6; ++q) p[q] = o[q];
    }
}

__global__ __launch_bounds__(TPB) void ncc_final(
    const double* __restrict__ part, float* __restrict__ outp)
{
    const int tid = threadIdx.x;
    __shared__ double sh[TPB / 64][6];
    double total = 0.0;   // only meaningful on tid 0

    for (int b = 0; b < NB; ++b) {
        const double* p = part + ((size_t)b * BPB + tid) * 6;
        double v[6];
        #pragma unroll
        for (int q = 0; q < 6; ++q) v[q] = p[q];
        #pragma unroll
        for (int q = 0; q < 6; ++q) v[q] = wave_reduce(v[q]);

        const int wave = tid >> 6, lane = tid & 63;
        if (lane == 0) {
            #pragma unroll
            for (int q = 0; q < 6; ++q) sh[wave][q] = v[q];
        }
        __syncthreads();

        if (tid == 0) {
            double o[6] = {0, 0, 0, 0, 0, 0};
            for (int w = 0; w < TPB / 64; ++w)
                for (int q = 0; q < 6; ++q) o[q] += sh[w][q];
            const double W = (double)VOL;
            double uI = o[0] / W, uJ = o[1] / W;
            double cross = o[4] - uJ * o[0] - uI * o[1] + uI * uJ * W;
            double Ivar  = o[2] - 2.0 * uI * o[0] + uI * uI * W;
            double Jvar  = o[3] - 2.0 * uJ * o[1] + uJ * uJ * W;
            double cc = (cross * cross) / (Ivar * Jvar + 1e-5);
            total += -cc * o[5];
        }
        __syncthreads();   // protect sh reuse across batches
    }

    if (tid == 0) outp[0] = (float)(total / ((double)NB * (double)VOL));
}

extern "C" void kernel_launch(void* const* d_in, const int* in_sizes, int n_in,
                              void* d_out, int out_size, void* d_ws, size_t ws_size,
                              hipStream_t stream)
{
    const float* I  = (const float*)d_in[0];   // out
    const float* J  = (const float*)d_in[1];   // y_pred
    const int*   CI = (const int*)d_in[2];     // out_ccl
    const int*   CJ = (const int*)d_in[3];     // y_ccl
    double* part = (double*)d_ws;              // NB*BPB*6 doubles = 192 KiB

    dim3 grid(BPB, NB);
    ncc_partial<<<grid, TPB, 0, stream>>>(I, J, CI, CJ, part);
    ncc_final<<<1, TPB, 0, stream>>>(part, (float*)d_out);
}

// Round 4
// 240.396 us; speedup vs baseline: 1.0788x; 1.0788x over previous
//
#include <hip/hip_runtime.h>

// NCC loss: per-batch global sums + masked count, then scalar combine.
// SHAPE (16,1,64,128,128): B=16 volumes of VOL=1048576 f32 elements.
// Latency-bound fix: batch 16 dwordx4 loads in flight, f32 hot-loop math,
// SoA partials + single parallel final block.

#define NB   16
#define VOL  (64 * 128 * 128)   // 1048576
#define BPB  256                // blocks per batch
#define TPB  256                // threads per block
#define EPT  16                 // elements per thread; BPB*TPB*EPT == VOL
#define NBLK (NB * BPB)         // 4096 total partial blocks

__device__ __forceinline__ double wave_reduce(double v) {
    #pragma unroll
    for (int off = 32; off > 0; off >>= 1) v += __shfl_down(v, off, 64);
    return v;
}

// f32 threshold TH such that (f32 x < TH) <=> ((double)x < 0.247) exactly.
__device__ __forceinline__ float mask_thresh() {
    const float c = 0.247f;
    if ((double)c < 0.247) return __uint_as_float(__float_as_uint(c) + 1u);
    return c;
}

__global__ __launch_bounds__(TPB) void ncc_partial(
    const float* __restrict__ I, const float* __restrict__ J,
    const int* __restrict__ CI, const int* __restrict__ CJ,
    double* __restrict__ part)
{
    const int b = blockIdx.y;
    const size_t base = (size_t)b * VOL + (size_t)blockIdx.x * (TPB * EPT);
    const int tid = threadIdx.x;

    const float4* __restrict__ I4 = reinterpret_cast<const float4*>(I + base);
    const float4* __restrict__ J4 = reinterpret_cast<const float4*>(J + base);
    const int4*   __restrict__ C4 = reinterpret_cast<const int4*>(CI + base);
    const int4*   __restrict__ D4 = reinterpret_cast<const int4*>(CJ + base);

    // ---- issue ALL loads before any compute: 16 dwordx4 in flight ----
    float4 iv[4]; float4 jv[4]; int4 cv[4]; int4 dv[4];
    #pragma unroll
    for (int k = 0; k < 4; ++k) iv[k] = I4[tid + k * TPB];
    #pragma unroll
    for (int k = 0; k < 4; ++k) jv[k] = J4[tid + k * TPB];
    #pragma unroll
    for (int k = 0; k < 4; ++k) cv[k] = C4[tid + k * TPB];
    #pragma unroll
    for (int k = 0; k < 4; ++k) dv[k] = D4[tid + k * TPB];

    const float TH = mask_thresh();
    float sI = 0.f, sJ = 0.f, sI2 = 0.f, sJ2 = 0.f, sIJ = 0.f;
    int cnt = 0;

    #pragma unroll
    for (int k = 0; k < 4; ++k) {
        float fi[4] = {iv[k].x, iv[k].y, iv[k].z, iv[k].w};
        float fj[4] = {jv[k].x, jv[k].y, jv[k].z, jv[k].w};
        int   ki[4] = {cv[k].x, cv[k].y, cv[k].z, cv[k].w};
        int   kj[4] = {dv[k].x, dv[k].y, dv[k].z, dv[k].w};
        #pragma unroll
        for (int e = 0; e < 4; ++e) {
            sI += fi[e];
            sJ += fj[e];
            sI2 = fmaf(fi[e], fi[e], sI2);
            sJ2 = fmaf(fj[e], fj[e], sJ2);
            sIJ = fmaf(fi[e], fj[e], sIJ);
            bool zI = (fi[e] < TH) && (ki[e] > 0);
            bool zJ = (fj[e] < TH) && (kj[e] > 0);
            cnt += (!zI && !zJ) ? 1 : 0;
        }
    }

    double v[6] = {(double)sI, (double)sJ, (double)sI2,
                   (double)sJ2, (double)sIJ, (double)cnt};
    #pragma unroll
    for (int q = 0; q < 6; ++q) v[q] = wave_reduce(v[q]);

    __shared__ double sh[TPB / 64][6];
    const int wave = tid >> 6, lane = tid & 63;
    if (lane == 0) {
        #pragma unroll
        for (int q = 0; q < 6; ++q) sh[wave][q] = v[q];
    }
    __syncthreads();

    if (tid == 0) {
        const int gb = b * BPB + blockIdx.x;   // global block number
        #pragma unroll
        for (int q = 0; q < 6; ++q) {
            double o = 0.0;
            for (int w = 0; w < TPB / 64; ++w) o += sh[w][q];
            part[(size_t)q * NBLK + gb] = o;   // SoA: coalesced for final pass
        }
    }
}

__global__ __launch_bounds__(1024) void ncc_final(
    const double* __restrict__ part, float* __restrict__ outp)
{
    const int tid = threadIdx.x;
    const int w = tid >> 6;     // wave w <-> batch w (16 waves)
    const int l = tid & 63;

    double v[6] = {0, 0, 0, 0, 0, 0};
    #pragma unroll
    for (int k = 0; k < BPB / 64; ++k) {
        const int p = w * BPB + k * 64 + l;
        #pragma unroll
        for (int q = 0; q < 6; ++q) v[q] += part[(size_t)q * NBLK + p];
    }
    #pragma unroll
    for (int q = 0; q < 6; ++q) v[q] = wave_reduce(v[q]);

    __shared__ double acc[NB];
    if (l == 0) {
        const double W = (double)VOL;
        double uI = v[0] / W, uJ = v[1] / W;
        double cross = v[4] - uJ * v[0] - uI * v[1] + uI * uJ * W;
        double Ivar  = v[2] - 2.0 * uI * v[0] + uI * uI * W;
        double Jvar  = v[3] - 2.0 * uJ * v[1] + uJ * uJ * W;
        double cc = (cross * cross) / (Ivar * Jvar + 1e-5);
        acc[w] = -cc * v[5];
    }
    __syncthreads();

    if (tid == 0) {
        double t = 0.0;
        for (int b = 0; b < NB; ++b) t += acc[b];
        outp[0] = (float)(t / ((double)NB * (double)VOL));
    }
}

extern "C" void kernel_launch(void* const* d_in, const int* in_sizes, int n_in,
                              void* d_out, int out_size, void* d_ws, size_t ws_size,
                              hipStream_t stream)
{
    const float* I  = (const float*)d_in[0];   // out
    const float* J  = (const float*)d_in[1];   // y_pred
    const int*   CI = (const int*)d_in[2];     // out_ccl
    const int*   CJ = (const int*)d_in[3];     // y_ccl
    double* part = (double*)d_ws;              // 6 * 4096 doubles = 192 KiB (SoA)

    dim3 grid(BPB, NB);
    ncc_partial<<<grid, TPB, 0, stream>>>(I, J, CI, CJ, part);
    ncc_final<<<1, 1024, 0, stream>>>(part, (float*)d_out);
}